// Round 15
// baseline (150.899 us; speedup 1.0000x reference)
//
#include <hip/hip_runtime.h>
#include <stdint.h>

// Problem constants (B=2048, N=16, T=1024)
#define T_STEPS 1024
#define NWORDS  256          // u64 mask words per batch (4 timesteps per word)
#define SCAN_BLOCK 64        // 1 wave: 4 batch-groups x 16 o; 2 chains per lane

typedef float f32x4 __attribute__((ext_vector_type(4)));

// ---------------------------------------------------------------------------
// Kernel 1 (R9-proven): blocks 0..B-1: spikes -> 16-bit masks (HBM-bound
// 128 MiB read, ~21 us). Block B: build the 64 KiB f64 byte table in global
// memory, concurrent with the mask blocks. All w[] indices compile-time.
// tab[s*4096 + byte*16 + o] = (lo-nibble ordered sum)+(hi-nibble ordered sum)
// == z_{2s} + z_{2s+1} with the EXACT association tree of the absmax-0 rounds.
// ---------------------------------------------------------------------------
__global__ __launch_bounds__(256) void k_maskify(const float* __restrict__ spike,
                                                 unsigned long long* __restrict__ masks,
                                                 const float* __restrict__ W,
                                                 double* __restrict__ tab,
                                                 int B) {
    const int b  = blockIdx.x;
    const int tc = threadIdx.x;
    if (b < B) {
        const float4* sp = reinterpret_cast<const float4*>(spike) + (size_t)b * (16 * NWORDS);
        unsigned int m0 = 0, m1 = 0, m2 = 0, m3 = 0;
#pragma unroll
        for (int i = 0; i < 16; ++i) {
            float4 v = sp[i * NWORDS + tc];
            m0 |= (v.x >= 0.5f) ? (1u << i) : 0u;
            m1 |= (v.y >= 0.5f) ? (1u << i) : 0u;
            m2 |= (v.z >= 0.5f) ? (1u << i) : 0u;
            m3 |= (v.w >= 0.5f) ? (1u << i) : 0u;
        }
        masks[(size_t)b * NWORDS + tc] =
            (unsigned long long)m0 | ((unsigned long long)m1 << 16) |
            ((unsigned long long)m2 << 32) | ((unsigned long long)m3 << 48);
    } else {
        const int o = tc & 15;
        double w[16];
#pragma unroll
        for (int j = 0; j < 16; ++j) w[j] = (double)W[o * 16 + j];
#pragma unroll
        for (int k = 0; k < 32; ++k) {                 // fully unrolled
            const int e    = tc + k * 256;
            const int byte = (e >> 4) & 255;
            const int s    = k >> 4;                   // COMPILE-TIME constant
            double slo = 0.0, shi = 0.0;
#pragma unroll
            for (int j = 0; j < 4; ++j) slo += (byte & (1 << j))  ? w[8 * s + j]     : 0.0;
#pragma unroll
            for (int j = 0; j < 4; ++j) shi += (byte & (16 << j)) ? w[8 * s + 4 + j] : 0.0;
            tab[s * 4096 + byte * 16 + o] = slo + shi; // = z_{2s} + z_{2s+1}
        }
    }
}

// ---------------------------------------------------------------------------
// Kernel 2: CUBA LIF scan — TWO independent chains per lane (ILP fills the
// exposed latency that was invariant across all R9-R14 pipeline variants).
// 64-thread blocks (1 wave), 256 blocks = 1 wave/CU on all 256 CUs.
// Lane (bb,o) runs batches bx = blk*8+bb and by = bx+4.
// Merged vmcnt ledger (hand-verified):
//   steady entry = 40 outstanding; body(w):
//   2xGLM m(w+4) -> 42; WAITV(22) forces [mx/my(w+2), Sx/Sy(w-2), Tx(w)8,
//   Ty(w)8]; 2xCOMPUTE(w) (+2 stores) -> 24; 2xTISSUE(w+2) -> 40.
// No SBAR between the two COMPUTEs: the compiler interleaves the two f64
// dependent chains. Numerics per chain byte-identical to the absmax-0 rounds.
// ---------------------------------------------------------------------------
__global__ __launch_bounds__(SCAN_BLOCK, 1) void k_scan(const double* __restrict__ tab,
                                                        const unsigned long long* __restrict__ masks,
                                                        float* __restrict__ out) {
    const int tid = threadIdx.x;
    const int bb  = tid >> 4;          // 0..3
    const int o   = tid & 15;
    const int bx  = blockIdx.x * 8 + bb;
    const int by  = bx + 4;

    const uint64_t tb     = (uint64_t)tab;
    const uint64_t mb     = (uint64_t)masks;
    const uint64_t ob_out = (uint64_t)out;
    const uint32_t ob0    = (uint32_t)(o * 8);
    const uint32_t ob1    = ob0 + 32768u;
    const uint32_t vb_mx  = (uint32_t)(bx * (NWORDS * 8));
    const uint32_t vb_my  = (uint32_t)(by * (NWORDS * 8));
    const uint32_t vb_ox  = (uint32_t)(bx * (T_STEPS * 4));
    const uint32_t vb_oy  = (uint32_t)(by * (T_STEPS * 4));
    const int grp_sh      = tid & 48;
    const bool writer     = (o == 0);

    double cx = 0.0, vx = 0.0, cy = 0.0, vy = 0.0;

    // Two depth-2 table sets per chain + rotating masks.
    double TAx_0, TAx_1, TAx_2, TAx_3, TAx_4, TAx_5, TAx_6, TAx_7;
    double TBx_0, TBx_1, TBx_2, TBx_3, TBx_4, TBx_5, TBx_6, TBx_7;
    double TAy_0, TAy_1, TAy_2, TAy_3, TAy_4, TAy_5, TAy_6, TAy_7;
    double TBy_0, TBy_1, TBy_2, TBy_3, TBy_4, TBy_5, TBy_6, TBy_7;
    unsigned long long MAx, MBx, MCx, MDx, MAy, MBy, MCy, MDy, qx0, qx1, qy0, qy1;

#define GLT(DST, VOFF) \
    asm volatile("global_load_dwordx2 %0, %1, %2" : "=v"(DST) : "v"(VOFF), "s"(tb))
#define GLM(DST, IDX, VBM) do { int _mi = (IDX); if (_mi > 255) _mi = 255;            \
    const uint32_t _vo = (VBM) + ((uint32_t)_mi << 3);                                \
    asm volatile("global_load_dwordx2 %0, %1, %2" : "=v"(DST) : "v"(_vo), "s"(mb)); } while (0)
#define WAITV(N) asm volatile("s_waitcnt vmcnt(" #N ")" ::: "memory")
#define SBAR __builtin_amdgcn_sched_barrier(0)

#define TISSUE(P, MW) do {                                                            \
    const uint32_t _lo = (uint32_t)(MW), _hi = (uint32_t)((MW) >> 32);                \
    uint32_t _a;                                                                      \
    _a = ob0 + ((_lo & 255u) << 7);          GLT(P##_0, _a);                          \
    _a = ob1 + (((_lo >> 8) & 255u) << 7);   GLT(P##_1, _a);                          \
    _a = ob0 + (((_lo >> 16) & 255u) << 7);  GLT(P##_2, _a);                          \
    _a = ob1 + ((_lo >> 24) << 7);           GLT(P##_3, _a);                          \
    _a = ob0 + ((_hi & 255u) << 7);          GLT(P##_4, _a);                          \
    _a = ob1 + (((_hi >> 8) & 255u) << 7);   GLT(P##_5, _a);                          \
    _a = ob0 + (((_hi >> 16) & 255u) << 7);  GLT(P##_6, _a);                          \
    _a = ob1 + ((_hi >> 24) << 7);           GLT(P##_7, _a);                          \
} while (0)

    // One recurrence step; numerics identical to the absmax-0 rounds.
#define ZSTEP(CC, VV, ZL, ZH, OWEL) do {                                              \
    const double _z = (ZL) + (ZH);                                                    \
    CC = fma(CC, 0.75, _z);                                                           \
    VV = fma(VV, 0.97, CC);                                                           \
    const bool _s = (VV >= 1.25);                                                     \
    const unsigned long long _bal = __ballot(_s);                                     \
    VV = _s ? 0.0 : VV;                                                               \
    const uint32_t _k = __popc((uint32_t)(_bal >> grp_sh) & 0xFFFFu);                 \
    OWEL = exp2f(fmaf((float)_k, 0.62581400f, 16.0f));                                \
} while (0)

#define COMPUTE(P, WD, CC, VV, VBOUT) do {                                            \
    f32x4 _ow;                                                                        \
    ZSTEP(CC, VV, P##_0, P##_1, _ow.x);                                               \
    ZSTEP(CC, VV, P##_2, P##_3, _ow.y);                                               \
    ZSTEP(CC, VV, P##_4, P##_5, _ow.z);                                               \
    ZSTEP(CC, VV, P##_6, P##_7, _ow.w);                                               \
    if (writer) {                                                                     \
        const uint32_t _vo = (VBOUT) + ((uint32_t)(WD) << 4);                         \
        asm volatile("global_store_dwordx4 %0, %1, %2"                                \
                     :: "v"(_vo), "v"(_ow), "s"(ob_out) : "memory");                  \
    }                                                                                 \
} while (0)

    // Body: both chains. NO SBAR between the two COMPUTEs (ILP interleave).
#define BODY(WD, P, MUX, MUY, MIX, MIY) do {                                          \
    GLM(MIX, (WD) + 4, vb_mx);                                                        \
    GLM(MIY, (WD) + 4, vb_my);                                                        \
    WAITV(22); SBAR;                                                                  \
    COMPUTE(P##x, WD, cx, vx, vb_ox);                                                 \
    COMPUTE(P##y, WD, cy, vy, vb_oy);                                                 \
    TISSUE(P##x, MUX);                                                                \
    TISSUE(P##y, MUY); SBAR;                                                          \
} while (0)

    asm volatile("s_waitcnt vmcnt(0) lgkmcnt(0)" ::: "memory");

    // Prologue: 8 masks in flight; tables for words 0,1 (both chains) issued.
    GLM(qx0, 0, vb_mx); GLM(qy0, 0, vb_my); GLM(qx1, 1, vb_mx); GLM(qy1, 1, vb_my);
    GLM(MAx, 2, vb_mx); GLM(MAy, 2, vb_my); GLM(MBx, 3, vb_mx); GLM(MBy, 3, vb_my);
    WAITV(4); SBAR;                 // q* ready; [MAx,MAy,MBx,MBy] outstanding
    TISSUE(TAx, qx0); TISSUE(TAy, qy0);
    TISSUE(TBx, qx1); TISSUE(TBy, qy1); SBAR;   // 4 + 32 = 36

    // Peeled body 0: force MA*,MB* + TA*(0) (oldest 20) -> keep 18.
    GLM(MCx, 4, vb_mx); GLM(MCy, 4, vb_my);     // 38
    WAITV(18); SBAR;
    COMPUTE(TAx, 0, cx, vx, vb_ox);
    COMPUTE(TAy, 0, cy, vy, vb_oy);             // +2 -> 20
    TISSUE(TAx, MAx); TISSUE(TAy, MAy); SBAR;   // -> 36

    // Peeled body 1: force TB*(1) (oldest 16) -> keep 22.
    GLM(MDx, 5, vb_mx); GLM(MDy, 5, vb_my);     // 38
    WAITV(22); SBAR;
    COMPUTE(TBx, 1, cx, vx, vb_ox);
    COMPUTE(TBy, 1, cy, vy, vb_oy);             // +2 -> 24
    TISSUE(TBx, MBx); TISSUE(TBy, MBy); SBAR;   // -> 40 == steady invariant

    // Steady: words 2..253, unrolled x4 (mask rotation period).
    for (int w = 2; w < 254; w += 4) {
        BODY(w,     TA, MCx, MCy, MAx, MAy);
        BODY(w + 1, TB, MDx, MDy, MBx, MBy);
        BODY(w + 2, TA, MAx, MAy, MCx, MCy);
        BODY(w + 3, TB, MBx, MBy, MDx, MDy);
    }

    // Epilogue: word 254 in TA*, word 255 in TB*.
    WAITV(20); SBAR;                // forces m*(256c), S*(252), T*(254)x16
    COMPUTE(TAx, 254, cx, vx, vb_ox);
    COMPUTE(TAy, 254, cy, vy, vb_oy);
    WAITV(2); SBAR;                 // forces T*(255)x16 (+older), keep S*(254)
    COMPUTE(TBx, 255, cx, vx, vb_ox);
    COMPUTE(TBy, 255, cy, vy, vb_oy);
    asm volatile("s_waitcnt vmcnt(0)" ::: "memory");  // drain stores

#undef GLT
#undef GLM
#undef WAITV
#undef SBAR
#undef TISSUE
#undef ZSTEP
#undef COMPUTE
#undef BODY
}

// ---------------------------------------------------------------------------
// Fallback (only if d_ws too small — never observed): R1-style scan.
// ---------------------------------------------------------------------------
__global__ __launch_bounds__(128) void k_scan_fb(const float* __restrict__ W,
                                                 const float* __restrict__ spike,
                                                 float* __restrict__ out) {
    __shared__ double ztab[4][16][16];
    __shared__ unsigned long long mlds[8][NWORDS];
    __shared__ float outtab[17];
    const int tid = threadIdx.x, bb = tid >> 4, o = tid & 15;
    for (int e = tid; e < 4 * 16 * 16; e += 128) {
        const int oo = e & 15, idx = (e >> 4) & 15, seg = e >> 8;
        double s = 0.0;
#pragma unroll
        for (int j = 0; j < 4; ++j)
            if (idx & (1 << j)) s += (double)W[oo * 16 + seg * 4 + j];
        ztab[seg][idx][oo] = s;
    }
    if (tid < 17) {
        const double ln2 = 0.69314718055994530941723212145818;
        const double l2c1 = log(2.0 * cosh(1.0));
        outtab[tid] = (float)exp((16.0 - (double)tid) * ln2 + (double)tid * l2c1);
    }
    {
        const int part = tid & 15;
        const float4* spb = reinterpret_cast<const float4*>(spike) +
                            (size_t)(blockIdx.x * 8 + bb) * (16 * NWORDS);
        for (int w = 0; w < 16; ++w) {
            const int tc = part * 16 + w;
            unsigned int m0 = 0, m1 = 0, m2 = 0, m3 = 0;
#pragma unroll
            for (int i = 0; i < 16; ++i) {
                float4 v = spb[i * NWORDS + tc];
                m0 |= (v.x >= 0.5f) ? (1u << i) : 0u;
                m1 |= (v.y >= 0.5f) ? (1u << i) : 0u;
                m2 |= (v.z >= 0.5f) ? (1u << i) : 0u;
                m3 |= (v.w >= 0.5f) ? (1u << i) : 0u;
            }
            mlds[bb][tc] = (unsigned long long)m0 | ((unsigned long long)m1 << 16) |
                           ((unsigned long long)m2 << 32) | ((unsigned long long)m3 << 48);
        }
    }
    __syncthreads();
    double c = 0.0, v = 0.0;
    const int b = blockIdx.x * 8 + bb;
    float* outp = out + (size_t)b * T_STEPS;
    const int grp_sh = tid & 48;
    const bool writer = (o == 0);
    for (int tg = 0; tg < NWORDS; ++tg) {
        const unsigned long long mw = mlds[bb][tg];
#pragma unroll
        for (int j = 0; j < 4; ++j) {
            const unsigned int m = (unsigned int)(mw >> (16 * j)) & 0xFFFFu;
            const double z = (ztab[0][m & 15][o] + ztab[1][(m >> 4) & 15][o]) +
                             (ztab[2][(m >> 8) & 15][o] + ztab[3][(m >> 12) & 15][o]);
            c = fma(c, 0.75, z);
            v = fma(v, 0.97, c);
            const bool s = (v >= 1.25);
            const unsigned long long bal = __ballot(s);
            v = s ? 0.0 : v;
            if (writer) outp[tg * 4 + j] = outtab[(int)__popcll((bal >> grp_sh) & 0xFFFFull)];
        }
    }
}

extern "C" void kernel_launch(void* const* d_in, const int* in_sizes, int n_in,
                              void* d_out, int out_size, void* d_ws, size_t ws_size,
                              hipStream_t stream) {
    const float* spike = (const float*)d_in[0];
    const float* W     = (const float*)d_in[1];
    float* out         = (float*)d_out;

    const int B = in_sizes[0] / (16 * T_STEPS);  // 2048

    const size_t mask_bytes = (size_t)B * NWORDS * sizeof(unsigned long long);  // 4 MiB
    const size_t tab_bytes  = 2 * 256 * 16 * sizeof(double);                    // 64 KiB

    if (ws_size >= mask_bytes + tab_bytes) {
        unsigned long long* masks = (unsigned long long*)d_ws;
        double* tab = (double*)((char*)d_ws + mask_bytes);
        // Grid B+1: blocks 0..B-1 build masks, block B builds the byte table.
        k_maskify<<<B + 1, 256, 0, stream>>>(spike, masks, W, tab, B);
        // 2 chains per lane: B/8 = 256 one-wave blocks (1 wave/CU, all CUs).
        k_scan<<<B / 8, SCAN_BLOCK, 0, stream>>>(tab, masks, out);
    } else {
        k_scan_fb<<<B / 8, 128, 0, stream>>>(W, spike, out);
    }
}

// Round 16
// 95.701 us; speedup vs baseline: 1.5768x; 1.5768x over previous
//
#include <hip/hip_runtime.h>
#include <stdint.h>

// Problem constants (B=2048, N=16, T=1024)
#define T_STEPS 1024
#define NWORDS  256          // u64 mask words per batch (4 timesteps per word)
#define NB      8            // batches per scan block
#define SCAN_BLOCK (NB * 16) // 128 threads: 8 batches x 16 output neurons

typedef float f32x4 __attribute__((ext_vector_type(4)));

// ---------------------------------------------------------------------------
// Kernel 1 (R9-proven): blocks 0..B-1: spikes -> 16-bit masks (HBM-bound
// 128 MiB read, ~21 us). Block B: build the 64 KiB f64 byte table in global
// memory, concurrent with the mask blocks. All w[] indices compile-time.
// tab[s*4096 + byte*16 + o] = (lo-nibble ordered sum)+(hi-nibble ordered sum)
// == z_{2s} + z_{2s+1} with the EXACT association tree of the absmax-0 rounds.
// ---------------------------------------------------------------------------
__global__ __launch_bounds__(256) void k_maskify(const float* __restrict__ spike,
                                                 unsigned long long* __restrict__ masks,
                                                 const float* __restrict__ W,
                                                 double* __restrict__ tab,
                                                 int B) {
    const int b  = blockIdx.x;
    const int tc = threadIdx.x;
    if (b < B) {
        const float4* sp = reinterpret_cast<const float4*>(spike) + (size_t)b * (16 * NWORDS);
        unsigned int m0 = 0, m1 = 0, m2 = 0, m3 = 0;
#pragma unroll
        for (int i = 0; i < 16; ++i) {
            float4 v = sp[i * NWORDS + tc];
            m0 |= (v.x >= 0.5f) ? (1u << i) : 0u;
            m1 |= (v.y >= 0.5f) ? (1u << i) : 0u;
            m2 |= (v.z >= 0.5f) ? (1u << i) : 0u;
            m3 |= (v.w >= 0.5f) ? (1u << i) : 0u;
        }
        masks[(size_t)b * NWORDS + tc] =
            (unsigned long long)m0 | ((unsigned long long)m1 << 16) |
            ((unsigned long long)m2 << 32) | ((unsigned long long)m3 << 48);
    } else {
        const int o = tc & 15;
        double w[16];
#pragma unroll
        for (int j = 0; j < 16; ++j) w[j] = (double)W[o * 16 + j];
#pragma unroll
        for (int k = 0; k < 32; ++k) {                 // fully unrolled
            const int e    = tc + k * 256;
            const int byte = (e >> 4) & 255;
            const int s    = k >> 4;                   // COMPILE-TIME constant
            double slo = 0.0, shi = 0.0;
#pragma unroll
            for (int j = 0; j < 4; ++j) slo += (byte & (1 << j))  ? w[8 * s + j]     : 0.0;
#pragma unroll
            for (int j = 0; j < 4; ++j) shi += (byte & (16 << j)) ? w[8 * s + 4 + j] : 0.0;
            tab[s * 4096 + byte * 16 + o] = slo + shi; // = z_{2s} + z_{2s+1}
        }
    }
}

// ---------------------------------------------------------------------------
// Kernel 2: CUBA LIF scan — R14's asm pipeline with the OUTPUT PATH MOVED
// OFF vmcnt: per-word results go to LDS (ds_write_b128, lgkm — never forced
// until the end), flushed once at kernel end with coalesced float4 stores.
// The loop's vmcnt stream is pure loads (8 table + 1 mask per word), so the
// in-order vmcnt retirement never has to wait on a store.
// Store-free ledger (hand-verified): steady entry = 18 outstanding
//   [m(w+2), T(w)x8, m(w+3), T(w+1)x8];
// body: GLM m(w+4) -> 19; WAITV(10) forces m(w+2)+T(w)x8; COMPUTE(w);
// LDS-write; TISSUE(w+2) -> 18. Peeled: WAITV(9) / WAITV(10); epi 9/0.
// Registers kept at the R14 minimum (2 table sets) to avoid the R13/R15
// spill trap. Numerics byte-identical to the absmax-0 rounds.
// ---------------------------------------------------------------------------
__global__ __launch_bounds__(SCAN_BLOCK, 1) void k_scan(const double* __restrict__ tab,
                                                        const unsigned long long* __restrict__ masks,
                                                        float* __restrict__ out) {
    __shared__ f32x4 lds_out[NB][NWORDS];   // 32 KiB output staging

    const int tid = threadIdx.x;
    const int bb  = tid >> 4;
    const int o   = tid & 15;
    const int b   = blockIdx.x * NB + bb;

    const uint64_t tb     = (uint64_t)tab;
    const uint64_t mb     = (uint64_t)masks;
    const uint32_t ob0    = (uint32_t)(o * 8);
    const uint32_t ob1    = ob0 + 32768u;
    const uint32_t vb_m   = (uint32_t)(b * (NWORDS * 8));
    const int grp_sh      = tid & 48;
    const bool writer     = (o == 0);

    double c = 0.0, v = 0.0;

    // TWO rotating table sets + 4 rotating mask regs + 2 prologue masks.
    double TA_0, TA_1, TA_2, TA_3, TA_4, TA_5, TA_6, TA_7;
    double TB_0, TB_1, TB_2, TB_3, TB_4, TB_5, TB_6, TB_7;
    unsigned long long MA, MB, MC, MD, q0, q1;

#define GLT(DST, VOFF) \
    asm volatile("global_load_dwordx2 %0, %1, %2" : "=v"(DST) : "v"(VOFF), "s"(tb))
#define GLM(DST, IDX) do { int _mi = (IDX); if (_mi > 255) _mi = 255;                 \
    const uint32_t _vo = vb_m + ((uint32_t)_mi << 3);                                 \
    asm volatile("global_load_dwordx2 %0, %1, %2" : "=v"(DST) : "v"(_vo), "s"(mb)); } while (0)
#define WAITV(N) asm volatile("s_waitcnt vmcnt(" #N ")" ::: "memory")
#define SBAR __builtin_amdgcn_sched_barrier(0)

#define TISSUE(P, MW) do {                                                            \
    const uint32_t _lo = (uint32_t)(MW), _hi = (uint32_t)((MW) >> 32);                \
    uint32_t _a;                                                                      \
    _a = ob0 + ((_lo & 255u) << 7);          GLT(P##_0, _a);                          \
    _a = ob1 + (((_lo >> 8) & 255u) << 7);   GLT(P##_1, _a);                          \
    _a = ob0 + (((_lo >> 16) & 255u) << 7);  GLT(P##_2, _a);                          \
    _a = ob1 + ((_lo >> 24) << 7);           GLT(P##_3, _a);                          \
    _a = ob0 + ((_hi & 255u) << 7);          GLT(P##_4, _a);                          \
    _a = ob1 + (((_hi >> 8) & 255u) << 7);   GLT(P##_5, _a);                          \
    _a = ob0 + (((_hi >> 16) & 255u) << 7);  GLT(P##_6, _a);                          \
    _a = ob1 + ((_hi >> 24) << 7);           GLT(P##_7, _a);                          \
} while (0)

    // One recurrence step; numerics identical to the absmax-0 rounds:
    // z = (z01)+(z23) via table halves, fma(c,0.75,z), fma(v,0.97,c).
#define ZSTEP(ZL, ZH, OWEL) do {                                                      \
    const double _z = (ZL) + (ZH);                                                    \
    c = fma(c, 0.75, _z);                                                             \
    v = fma(v, 0.97, c);                                                              \
    const bool _s = (v >= 1.25);                                                      \
    const unsigned long long _bal = __ballot(_s);                                     \
    v = _s ? 0.0 : v;                                                                 \
    const uint32_t _k = __popc((uint32_t)(_bal >> grp_sh) & 0xFFFFu);                 \
    OWEL = exp2f(fmaf((float)_k, 0.62581400f, 16.0f));                                \
} while (0)

    // Output word -> LDS (lgkm path, NOT vmcnt). One ds_write_b128 by o==0.
#define COMPUTE(P, WD) do {                                                           \
    f32x4 _ow;                                                                        \
    ZSTEP(P##_0, P##_1, _ow.x);                                                       \
    ZSTEP(P##_2, P##_3, _ow.y);                                                       \
    ZSTEP(P##_4, P##_5, _ow.z);                                                       \
    ZSTEP(P##_6, P##_7, _ow.w);                                                       \
    if (writer) lds_out[bb][WD] = _ow;                                                \
} while (0)

#define BODY(WD, P, MU, MI) do {                                                      \
    GLM(MI, (WD) + 4);                                                                \
    WAITV(10); SBAR;                                                                  \
    COMPUTE(P, WD);                                                                   \
    TISSUE(P, MU); SBAR;                                                              \
} while (0)

    asm volatile("s_waitcnt vmcnt(0) lgkmcnt(0)" ::: "memory");

    // Prologue: masks 0..3 in flight; tables for words 0,1 issued.
    GLM(q0, 0); GLM(q1, 1); GLM(MA, 2); GLM(MB, 3);
    WAITV(2); SBAR;                 // m0,m1 ready; [MA,MB] outstanding
    TISSUE(TA, q0);
    TISSUE(TB, q1); SBAR;           // outstanding: MA,MB,TA8,TB8 = 18

    // Peeled body 0: GLM m4 -> 19; force MA,MB,TA8 -> WAITV(9).
    GLM(MC, 4);
    WAITV(9); SBAR;
    COMPUTE(TA, 0);
    TISSUE(TA, MA); SBAR;           // T(2): [TB8, MC, TA8] = 17

    // Peeled body 1: GLM m5 -> 18; force TB8 -> WAITV(10).
    GLM(MD, 5);
    WAITV(10); SBAR;
    COMPUTE(TB, 1);
    TISSUE(TB, MB); SBAR;           // T(3): [MC, TA8, MD, TB8] = 18 steady

    // Steady: words 2..253, unrolled x4 (mask rotation period).
    for (int w = 2; w < 254; w += 4) {
        BODY(w,     TA, MC, MA);    // uses m(w+2)=MC, loads m(w+4)->MA
        BODY(w + 1, TB, MD, MB);
        BODY(w + 2, TA, MA, MC);
        BODY(w + 3, TB, MB, MD);
    }

    // Epilogue: word 254 in TA, word 255 in TB.
    WAITV(9); SBAR;                 // force T(254)x8 (+1 older mask)
    COMPUTE(TA, 254);
    WAITV(0); SBAR;                 // drain everything; T(255) ready
    COMPUTE(TB, 255);

    // Flush LDS -> global, coalesced float4 (the ONLY global stores).
    __syncthreads();
    {
        float4* gout = reinterpret_cast<float4*>(out) + (size_t)blockIdx.x * NB * (T_STEPS / 4);
        const float4* ls = reinterpret_cast<const float4*>(&lds_out[0][0]);
        for (int i = tid; i < NB * NWORDS; i += SCAN_BLOCK) gout[i] = ls[i];
    }

#undef GLT
#undef GLM
#undef WAITV
#undef SBAR
#undef TISSUE
#undef ZSTEP
#undef COMPUTE
#undef BODY
}

// ---------------------------------------------------------------------------
// Fallback (only if d_ws too small — never observed): R1-style scan.
// ---------------------------------------------------------------------------
__global__ __launch_bounds__(SCAN_BLOCK) void k_scan_fb(const float* __restrict__ W,
                                                        const float* __restrict__ spike,
                                                        float* __restrict__ out) {
    __shared__ double ztab[4][16][16];
    __shared__ unsigned long long mlds[NB][NWORDS];
    __shared__ float outtab[17];
    const int tid = threadIdx.x, bb = tid >> 4, o = tid & 15;
    for (int e = tid; e < 4 * 16 * 16; e += SCAN_BLOCK) {
        const int oo = e & 15, idx = (e >> 4) & 15, seg = e >> 8;
        double s = 0.0;
#pragma unroll
        for (int j = 0; j < 4; ++j)
            if (idx & (1 << j)) s += (double)W[oo * 16 + seg * 4 + j];
        ztab[seg][idx][oo] = s;
    }
    if (tid < 17) {
        const double ln2 = 0.69314718055994530941723212145818;
        const double l2c1 = log(2.0 * cosh(1.0));
        outtab[tid] = (float)exp((16.0 - (double)tid) * ln2 + (double)tid * l2c1);
    }
    {
        const int part = tid & 15;
        const float4* spb = reinterpret_cast<const float4*>(spike) +
                            (size_t)(blockIdx.x * NB + bb) * (16 * NWORDS);
        for (int w = 0; w < 16; ++w) {
            const int tc = part * 16 + w;
            unsigned int m0 = 0, m1 = 0, m2 = 0, m3 = 0;
#pragma unroll
            for (int i = 0; i < 16; ++i) {
                float4 v = spb[i * NWORDS + tc];
                m0 |= (v.x >= 0.5f) ? (1u << i) : 0u;
                m1 |= (v.y >= 0.5f) ? (1u << i) : 0u;
                m2 |= (v.z >= 0.5f) ? (1u << i) : 0u;
                m3 |= (v.w >= 0.5f) ? (1u << i) : 0u;
            }
            mlds[bb][tc] = (unsigned long long)m0 | ((unsigned long long)m1 << 16) |
                           ((unsigned long long)m2 << 32) | ((unsigned long long)m3 << 48);
        }
    }
    __syncthreads();
    double c = 0.0, v = 0.0;
    const int b = blockIdx.x * NB + bb;
    float* outp = out + (size_t)b * T_STEPS;
    const int grp_sh = tid & 48;
    const bool writer = (o == 0);
    for (int tg = 0; tg < NWORDS; ++tg) {
        const unsigned long long mw = mlds[bb][tg];
#pragma unroll
        for (int j = 0; j < 4; ++j) {
            const unsigned int m = (unsigned int)(mw >> (16 * j)) & 0xFFFFu;
            const double z = (ztab[0][m & 15][o] + ztab[1][(m >> 4) & 15][o]) +
                             (ztab[2][(m >> 8) & 15][o] + ztab[3][(m >> 12) & 15][o]);
            c = fma(c, 0.75, z);
            v = fma(v, 0.97, c);
            const bool s = (v >= 1.25);
            const unsigned long long bal = __ballot(s);
            v = s ? 0.0 : v;
            if (writer) outp[tg * 4 + j] = outtab[(int)__popcll((bal >> grp_sh) & 0xFFFFull)];
        }
    }
}

extern "C" void kernel_launch(void* const* d_in, const int* in_sizes, int n_in,
                              void* d_out, int out_size, void* d_ws, size_t ws_size,
                              hipStream_t stream) {
    const float* spike = (const float*)d_in[0];
    const float* W     = (const float*)d_in[1];
    float* out         = (float*)d_out;

    const int B = in_sizes[0] / (16 * T_STEPS);  // 2048

    const size_t mask_bytes = (size_t)B * NWORDS * sizeof(unsigned long long);  // 4 MiB
    const size_t tab_bytes  = 2 * 256 * 16 * sizeof(double);                    // 64 KiB

    if (ws_size >= mask_bytes + tab_bytes) {
        unsigned long long* masks = (unsigned long long*)d_ws;
        double* tab = (double*)((char*)d_ws + mask_bytes);
        // Grid B+1: blocks 0..B-1 build masks, block B builds the byte table.
        k_maskify<<<B + 1, 256, 0, stream>>>(spike, masks, W, tab, B);
        k_scan<<<B / NB, SCAN_BLOCK, 0, stream>>>(tab, masks, out);
    } else {
        k_scan_fb<<<B / NB, SCAN_BLOCK, 0, stream>>>(W, spike, out);
    }
}

// Round 19
// 95.607 us; speedup vs baseline: 1.5783x; 1.0010x over previous
//
#include <hip/hip_runtime.h>
#include <stdint.h>

// Problem constants (B=2048, N=16, T=1024)
#define T_STEPS 1024
#define NWORDS  256          // u64 mask words per batch (4 timesteps per word)
#define NB      8            // batches per scan block
#define SCAN_BLOCK (NB * 16) // 128 threads: 8 batches x 16 output neurons

typedef float f32x4 __attribute__((ext_vector_type(4)));

// ---------------------------------------------------------------------------
// Kernel 1: spikes -> 16-bit masks, 4 timesteps per u64 (HBM-bound 128 MiB).
// Proven since R1.
// ---------------------------------------------------------------------------
__global__ __launch_bounds__(256) void k_maskify(const float* __restrict__ spike,
                                                 unsigned long long* __restrict__ masks) {
    const int b  = blockIdx.x;
    const int tc = threadIdx.x;
    const float4* sp = reinterpret_cast<const float4*>(spike) + (size_t)b * (16 * NWORDS);
    unsigned int m0 = 0, m1 = 0, m2 = 0, m3 = 0;
#pragma unroll
    for (int i = 0; i < 16; ++i) {
        float4 v = sp[i * NWORDS + tc];
        m0 |= (v.x >= 0.5f) ? (1u << i) : 0u;
        m1 |= (v.y >= 0.5f) ? (1u << i) : 0u;
        m2 |= (v.z >= 0.5f) ? (1u << i) : 0u;
        m3 |= (v.w >= 0.5f) ? (1u << i) : 0u;
    }
    masks[(size_t)b * NWORDS + tc] =
        (unsigned long long)m0 | ((unsigned long long)m1 << 16) |
        ((unsigned long long)m2 << 32) | ((unsigned long long)m3 << 48);
}

// ---------------------------------------------------------------------------
// Kernel 2: CUBA LIF scan — LDS byte-table + hand-owned UNIFIED lgkmcnt
// ledger. The R9-R16 invariant (~65 cyc per VMEM instr, depth-insensitive)
// says the VMEM pipe itself is the cap, so table+mask traffic moves to LDS
// (lgkm pipe); only the 1 output store/word stays on vmcnt.
// R10's failure mode (mixed C++ LDS reads corrupting the hand ledger) is
// eliminated: EVERY ds op in the loop is inline asm; addresses come from the
// real &ztab8/&mlds pointers (no base-0 assumption); SBAR after every wait.
// Ledger (hand-traced): steady entry = 18 outstanding DS ops
//   [T(w)x8, m(w+2), T(w+1)x8, m(w+3)];
// body: WAITLG(9) retires T(w)x8+m(w+2); COMPUTE(w) (+1 vmcnt store);
// TISSUE(w+2) x8; DSRM m(w+4) -> 18. Prologue establishes the pattern;
// epilogue WAITLG(9)/WAITLG(0). WAITV(16) per body bounds the store queue.
// Numerics byte-identical to the absmax-0 rounds: table entry =
// (lo-nibble ordered sum)+(hi-nibble ordered sum); z = B0+B1;
// c = fma(c,0.75,z); v = fma(v,0.97,c).
// ---------------------------------------------------------------------------
__global__ __launch_bounds__(SCAN_BLOCK, 1) void k_scan(const float* __restrict__ W,
                                                        const unsigned long long* __restrict__ masks,
                                                        float* __restrict__ out) {
    __shared__ double ztab8[2][256][17];              // 68 KiB, row 136 B (bank-spread)
    __shared__ unsigned long long mlds[NB][NWORDS + 1]; // 16.1 KiB, row 2056 B

    const int tid = threadIdx.x;
    const int bb  = tid >> 4;
    const int o   = tid & 15;
    const int b   = blockIdx.x * NB + bb;

    // --- Build byte table (R4/R14-proven construction; only the pad differs).
    {
        double w[16];
#pragma unroll
        for (int j = 0; j < 16; ++j) w[j] = (double)W[o * 16 + j];
#pragma unroll
        for (int k = 0; k < 64; ++k) {
            const int e    = tid + k * SCAN_BLOCK;
            const int byte = (e >> 4) & 255;
            const int s    = k >> 5;               // COMPILE-TIME constant
            double slo = 0.0, shi = 0.0;
#pragma unroll
            for (int j = 0; j < 4; ++j) slo += (byte & (1 << j))  ? w[8 * s + j]     : 0.0;
#pragma unroll
            for (int j = 0; j < 4; ++j) shi += (byte & (16 << j)) ? w[8 * s + 4 + j] : 0.0;
            ztab8[s][byte][o] = slo + shi;         // = z_{2s} + z_{2s+1}
        }
    }
    // --- Stage masks global->LDS (coalesced reads; padded rows).
    {
        const unsigned long long* src = masks + (size_t)blockIdx.x * NB * NWORDS;
        for (int e = tid; e < NB * NWORDS; e += SCAN_BLOCK)
            mlds[e >> 8][e & 255] = src[e];
    }
    __syncthreads();

    // Real LDS byte addresses (no base-0 assumption — R10's fatal shortcut).
    const uint32_t tl0 = (uint32_t)(uintptr_t)(&ztab8[0][0][0]) + (uint32_t)(o * 8);
    const uint32_t tl1 = (uint32_t)(uintptr_t)(&ztab8[1][0][0]) + (uint32_t)(o * 8);
    const uint32_t mlb = (uint32_t)(uintptr_t)(&mlds[bb][0]);

    const uint64_t ob_out = (uint64_t)out;
    const uint32_t vb_out = (uint32_t)(b * (T_STEPS * 4));
    const int grp_sh      = tid & 48;
    const bool writer     = (o == 0);

    double c = 0.0, v = 0.0;

    // TWO rotating table sets + rotating mask regs (all static names).
    double TA_0, TA_1, TA_2, TA_3, TA_4, TA_5, TA_6, TA_7;
    double TB_0, TB_1, TB_2, TB_3, TB_4, TB_5, TB_6, TB_7;
    unsigned long long MA, MB, MC, MD, q0, q1;

#define DSR(DST, ADDR) asm volatile("ds_read_b64 %0, %1" : "=v"(DST) : "v"(ADDR))
#define DSRM(DST, IDX) do { int _mi = (IDX); if (_mi > 255) _mi = 255;                \
    const uint32_t _a = mlb + ((uint32_t)_mi << 3); DSR(DST, _a); } while (0)
#define WAITLG(N) asm volatile("s_waitcnt lgkmcnt(" #N ")" ::: "memory")
#define WAITV(N)  asm volatile("s_waitcnt vmcnt(" #N ")" ::: "memory")
#define SBAR __builtin_amdgcn_sched_barrier(0)

    // 8 ds_read_b64 for one mask word. Within a 16-lane group: same byte,
    // o*8 stride -> each lane owns one even/odd bank pair: conflict-free.
#define TISSUE(P, MW) do {                                                            \
    const uint32_t _lo = (uint32_t)(MW), _hi = (uint32_t)((MW) >> 32);                \
    uint32_t _a;                                                                      \
    _a = tl0 + (_lo & 255u) * 136u;         DSR(P##_0, _a);                           \
    _a = tl1 + ((_lo >> 8) & 255u) * 136u;  DSR(P##_1, _a);                           \
    _a = tl0 + ((_lo >> 16) & 255u) * 136u; DSR(P##_2, _a);                           \
    _a = tl1 + (_lo >> 24) * 136u;          DSR(P##_3, _a);                           \
    _a = tl0 + (_hi & 255u) * 136u;         DSR(P##_4, _a);                           \
    _a = tl1 + ((_hi >> 8) & 255u) * 136u;  DSR(P##_5, _a);                           \
    _a = tl0 + ((_hi >> 16) & 255u) * 136u; DSR(P##_6, _a);                           \
    _a = tl1 + (_hi >> 24) * 136u;          DSR(P##_7, _a);                           \
} while (0)

    // One recurrence step; numerics identical to the absmax-0 rounds.
#define ZSTEP(ZL, ZH, OWEL) do {                                                      \
    const double _z = (ZL) + (ZH);                                                    \
    c = fma(c, 0.75, _z);                                                             \
    v = fma(v, 0.97, c);                                                              \
    const bool _s = (v >= 1.25);                                                      \
    const unsigned long long _bal = __ballot(_s);                                     \
    v = _s ? 0.0 : v;                                                                 \
    const uint32_t _k = __popc((uint32_t)(_bal >> grp_sh) & 0xFFFFu);                 \
    OWEL = exp2f(fmaf((float)_k, 0.62581400f, 16.0f));                                \
} while (0)

#define COMPUTE(P, WD) do {                                                           \
    f32x4 _ow;                                                                        \
    ZSTEP(P##_0, P##_1, _ow.x);                                                       \
    ZSTEP(P##_2, P##_3, _ow.y);                                                       \
    ZSTEP(P##_4, P##_5, _ow.z);                                                       \
    ZSTEP(P##_6, P##_7, _ow.w);                                                       \
    if (writer) {                                                                     \
        const uint32_t _vo = vb_out + ((uint32_t)(WD) << 4);                          \
        asm volatile("global_store_dwordx4 %0, %1, %2"                                \
                     :: "v"(_vo), "v"(_ow), "s"(ob_out) : "memory");                  \
    }                                                                                 \
} while (0)

#define BODY(WD, P, MU, MI) do {                                                      \
    WAITLG(9); WAITV(16); SBAR;    /* retire T(WD)x8 + m(WD+2); bound stores */       \
    COMPUTE(P, WD);                                                                   \
    TISSUE(P, MU);                 /* issue word WD+2 into the freed set */           \
    DSRM(MI, (WD) + 4); SBAR;                                                         \
} while (0)

    asm volatile("s_waitcnt vmcnt(0) lgkmcnt(0)" ::: "memory");  // clean ledgers

    // Prologue — establish the steady pattern [T(0)8, m(2), T(1)8, m(3)]:
    DSRM(q0, 0); DSRM(q1, 1);
    WAITLG(0); SBAR;                // q0,q1 ready
    TISSUE(TA, q0); DSRM(MA, 2);
    TISSUE(TB, q1); DSRM(MB, 3); SBAR;   // 18 outstanding, steady order

    // Steady: words 0..253 (uniform bodies; mask rotation period 4).
    for (int w = 0; w < 252; w += 4) {
        BODY(w,     TA, MA, MC);    // uses m(w+2)=MA, loads m(w+4)->MC
        BODY(w + 1, TB, MB, MD);
        BODY(w + 2, TA, MC, MA);
        BODY(w + 3, TB, MD, MB);
    }
    BODY(252, TA, MA, MC);
    BODY(253, TB, MB, MD);

    // Epilogue: word 254 in TA, word 255 in TB.
    WAITLG(9); SBAR;                // retires T(254)x8 + m(256c)
    COMPUTE(TA, 254);
    WAITLG(0); SBAR;                // retires T(255)x8 + m(257c)
    COMPUTE(TB, 255);
    asm volatile("s_waitcnt vmcnt(0)" ::: "memory");  // drain stores

#undef DSR
#undef DSRM
#undef WAITLG
#undef WAITV
#undef SBAR
#undef TISSUE
#undef ZSTEP
#undef COMPUTE
#undef BODY
}

// ---------------------------------------------------------------------------
// Fallback (only if d_ws too small — never observed): R1-style scan.
// ---------------------------------------------------------------------------
__global__ __launch_bounds__(SCAN_BLOCK) void k_scan_fb(const float* __restrict__ W,
                                                        const float* __restrict__ spike,
                                                        float* __restrict__ out) {
    __shared__ double ztab[4][16][16];
    __shared__ unsigned long long mlds[NB][NWORDS];
    __shared__ float outtab[17];
    const int tid = threadIdx.x, bb = tid >> 4, o = tid & 15;
    for (int e = tid; e < 4 * 16 * 16; e += SCAN_BLOCK) {
        const int oo = e & 15, idx = (e >> 4) & 15, seg = e >> 8;
        double s = 0.0;
#pragma unroll
        for (int j = 0; j < 4; ++j)
            if (idx & (1 << j)) s += (double)W[oo * 16 + seg * 4 + j];
        ztab[seg][idx][oo] = s;
    }
    if (tid < 17) {
        const double ln2 = 0.69314718055994530941723212145818;
        const double l2c1 = log(2.0 * cosh(1.0));
        outtab[tid] = (float)exp((16.0 - (double)tid) * ln2 + (double)tid * l2c1);
    }
    {
        const int part = tid & 15;
        const float4* spb = reinterpret_cast<const float4*>(spike) +
                            (size_t)(blockIdx.x * NB + bb) * (16 * NWORDS);
        for (int w = 0; w < 16; ++w) {
            const int tc = part * 16 + w;
            unsigned int m0 = 0, m1 = 0, m2 = 0, m3 = 0;
#pragma unroll
            for (int i = 0; i < 16; ++i) {
                float4 v = spb[i * NWORDS + tc];
                m0 |= (v.x >= 0.5f) ? (1u << i) : 0u;
                m1 |= (v.y >= 0.5f) ? (1u << i) : 0u;
                m2 |= (v.z >= 0.5f) ? (1u << i) : 0u;
                m3 |= (v.w >= 0.5f) ? (1u << i) : 0u;
            }
            mlds[bb][tc] = (unsigned long long)m0 | ((unsigned long long)m1 << 16) |
                           ((unsigned long long)m2 << 32) | ((unsigned long long)m3 << 48);
        }
    }
    __syncthreads();
    double c = 0.0, v = 0.0;
    const int b = blockIdx.x * NB + bb;
    float* outp = out + (size_t)b * T_STEPS;
    const int grp_sh = tid & 48;
    const bool writer = (o == 0);
    for (int tg = 0; tg < NWORDS; ++tg) {
        const unsigned long long mw = mlds[bb][tg];
#pragma unroll
        for (int j = 0; j < 4; ++j) {
            const unsigned int m = (unsigned int)(mw >> (16 * j)) & 0xFFFFu;
            const double z = (ztab[0][m & 15][o] + ztab[1][(m >> 4) & 15][o]) +
                             (ztab[2][(m >> 8) & 15][o] + ztab[3][(m >> 12) & 15][o]);
            c = fma(c, 0.75, z);
            v = fma(v, 0.97, c);
            const bool s = (v >= 1.25);
            const unsigned long long bal = __ballot(s);
            v = s ? 0.0 : v;
            if (writer) outp[tg * 4 + j] = outtab[(int)__popcll((bal >> grp_sh) & 0xFFFFull)];
        }
    }
}

extern "C" void kernel_launch(void* const* d_in, const int* in_sizes, int n_in,
                              void* d_out, int out_size, void* d_ws, size_t ws_size,
                              hipStream_t stream) {
    const float* spike = (const float*)d_in[0];
    const float* W     = (const float*)d_in[1];
    float* out         = (float*)d_out;

    const int B = in_sizes[0] / (16 * T_STEPS);  // 2048

    const size_t mask_bytes = (size_t)B * NWORDS * sizeof(unsigned long long);  // 4 MiB

    if (ws_size >= mask_bytes) {
        unsigned long long* masks = (unsigned long long*)d_ws;
        k_maskify<<<B, 256, 0, stream>>>(spike, masks);
        k_scan<<<B / NB, SCAN_BLOCK, 0, stream>>>(W, masks, out);
    } else {
        k_scan_fb<<<B / NB, SCAN_BLOCK, 0, stream>>>(W, spike, out);
    }
}